// Round 5
// baseline (173.474 us; speedup 1.0000x reference)
//
#include <hip/hip_runtime.h>
#include <hip/hip_fp16.h>

#define N 8192
#define D 128
#define MARGIN 0.3f

typedef __fp16 half_t;
typedef __attribute__((ext_vector_type(8))) __fp16 half8;
typedef __attribute__((ext_vector_type(4))) float f32x4;

// ---------------- prep: fp32 -> fp16, exact fp32 norms, zero accumulators ----
__global__ void triplet_prep(const float* __restrict__ x,
                             half_t* __restrict__ xh,
                             float* __restrict__ norms,
                             float* __restrict__ gacc) {
    const int gt = blockIdx.x * 256 + threadIdx.x;
    if (gt < 3) gacc[gt] = 0.f;          // [0]=sum [1]=count [2]=ticket
    const int row  = gt >> 6;            // one wave per row
    const int lane = gt & 63;
    const float* rp = x + (size_t)row * D;
    float a0 = rp[lane], a1 = rp[lane + 64];
    xh[(size_t)row * D + lane]      = (half_t)a0;
    xh[(size_t)row * D + lane + 64] = (half_t)a1;
    float s = fmaf(a0, a0, a1 * a1);
#pragma unroll
    for (int o = 32; o > 0; o >>= 1) s += __shfl_xor(s, o);
    if (lane == 0) norms[row] = s;
}

// ---------------- main: barrier-free register GEMM over L2 -------------------
// 4096 independent waves (1024 blocks x 4). wave = rowgroup (64 rows) x chunk (256 cols).
// A frags in registers pre-scaled by -2; acc chain seeded with nj so acc = nj - 2*g.
// B frags global->reg, 2-deep rotating prefetch. No LDS, no barriers.

#define PF(BN, LJN, NJN, SN) {                                          \
    const int jn = colbase + (SN) * 16 + lcol;                          \
    const half_t* bp = xh + (size_t)jn * D + lrow * 8;                  \
    BN[0] = *(const half8*)bp;                                          \
    BN[1] = *(const half8*)(bp + 32);                                   \
    BN[2] = *(const half8*)(bp + 64);                                   \
    BN[3] = *(const half8*)(bp + 96);                                   \
    LJN = labels[jn];                                                   \
    NJN = norms[jn];                                                    \
}

#define POISON(ACC) {                                                   \
    _Pragma("unroll")                                                   \
    for (int rg = 0; rg < 4; ++rg)                                      \
        ACC[rg] = (diagl && rg == drg) ? -1e30f : ACC[rg];              \
}

#define EPI(ACC, FI, LJC) {                                             \
    _Pragma("unroll")                                                   \
    for (int rg = 0; rg < 4; ++rg) {                                    \
        float c = ACC[rg];                                              \
        bool same = (li[(FI) * 4 + rg] == (LJC));                       \
        mpos[(FI)*4+rg] = same ? fmaxf(mpos[(FI)*4+rg], c) : mpos[(FI)*4+rg]; \
        mneg[(FI)*4+rg] = same ? mneg[(FI)*4+rg] : fminf(mneg[(FI)*4+rg], c); \
    }                                                                   \
}

#define COMP(BC, LJC, NJC, S) {                                         \
    f32x4 njq = {NJC, NJC, NJC, NJC};                                   \
    __builtin_amdgcn_s_setprio(1);                                      \
    f32x4 a0 = __builtin_amdgcn_mfma_f32_16x16x32_f16(af[0][0], BC[0], njq, 0, 0, 0); \
    f32x4 a1 = __builtin_amdgcn_mfma_f32_16x16x32_f16(af[1][0], BC[0], njq, 0, 0, 0); \
    f32x4 a2 = __builtin_amdgcn_mfma_f32_16x16x32_f16(af[2][0], BC[0], njq, 0, 0, 0); \
    f32x4 a3 = __builtin_amdgcn_mfma_f32_16x16x32_f16(af[3][0], BC[0], njq, 0, 0, 0); \
    _Pragma("unroll")                                                   \
    for (int ks = 1; ks < 4; ++ks) {                                    \
        a0 = __builtin_amdgcn_mfma_f32_16x16x32_f16(af[0][ks], BC[ks], a0, 0, 0, 0); \
        a1 = __builtin_amdgcn_mfma_f32_16x16x32_f16(af[1][ks], BC[ks], a1, 0, 0, 0); \
        a2 = __builtin_amdgcn_mfma_f32_16x16x32_f16(af[2][ks], BC[ks], a2, 0, 0, 0); \
        a3 = __builtin_amdgcn_mfma_f32_16x16x32_f16(af[3][ks], BC[ks], a3, 0, 0, 0); \
    }                                                                   \
    __builtin_amdgcn_s_setprio(0);                                      \
    const int dj = colbase + (S) * 16 - rowbase;                        \
    if (dj == 0)       POISON(a0)                                       \
    else if (dj == 16) POISON(a1)                                       \
    else if (dj == 32) POISON(a2)                                       \
    else if (dj == 48) POISON(a3)                                       \
    EPI(a0, 0, LJC)                                                     \
    EPI(a1, 1, LJC)                                                     \
    EPI(a2, 2, LJC)                                                     \
    EPI(a3, 3, LJC)                                                     \
}

__launch_bounds__(256, 4)
__global__ void triplet_main(const half_t* __restrict__ xh,
                             const float* __restrict__ norms,
                             const int* __restrict__ labels,
                             float* __restrict__ ppos,
                             float* __restrict__ pneg) {
    const int tid   = threadIdx.x;
    const int lane  = tid & 63;
    const int gw    = blockIdx.x * 4 + (tid >> 6);  // 0..4095
    const int rowg  = gw >> 5;                      // 0..127
    const int chunk = gw & 31;                      // 0..31
    const int lrow  = lane >> 4;                    // 0..3 (k-slot group / C row-group)
    const int lcol  = lane & 15;                    // 0..15 (A/B row, C col)
    const int rowbase = rowg * 64;
    const int colbase = chunk * 256;
    const bool diagl = (lrow == (lcol >> 2));
    const int  drg   = lcol & 3;

    // A fragments: row = rowbase + fi*16 + lcol, k = ks*32 + lrow*8; pre-scaled by -2
    half8 af[4][4];
#pragma unroll
    for (int fi = 0; fi < 4; ++fi) {
        const half_t* ap = xh + (size_t)(rowbase + fi * 16 + lcol) * D + lrow * 8;
#pragma unroll
        for (int ks = 0; ks < 4; ++ks)
            af[fi][ks] = *(const half8*)(ap + ks * 32) * (half_t)(-2.0f);
    }

    // owned C-rows: rowbase + fi*16 + lrow*4 + rg
    const int ibase = rowbase + lrow * 4;
    int li[16];
#pragma unroll
    for (int fi = 0; fi < 4; ++fi)
#pragma unroll
        for (int rg = 0; rg < 4; ++rg)
            li[fi * 4 + rg] = labels[ibase + fi * 16 + rg];

    float mpos[16], mneg[16];
#pragma unroll
    for (int r = 0; r < 16; ++r) { mpos[r] = -1e38f; mneg[r] = 1e38f; }

    // 16 sub-steps of 16 cols, 2-deep rotating register prefetch, no barriers
    half8 b0[4], b1[4];
    int lj0, lj1; float nj0, nj1;
    PF(b0, lj0, nj0, 0)
    PF(b1, lj1, nj1, 1)
    for (int s = 0; s < 14; s += 2) {
        COMP(b0, lj0, nj0, s)
        PF(b0, lj0, nj0, s + 2)
        COMP(b1, lj1, nj1, s + 1)
        PF(b1, lj1, nj1, s + 3)
    }
    COMP(b0, lj0, nj0, 14)
    COMP(b1, lj1, nj1, 15)

    // reduce across the 16 col-lanes (C cols live on lcol)
#pragma unroll
    for (int o = 1; o < 16; o <<= 1) {
#pragma unroll
        for (int r = 0; r < 16; ++r) {
            mpos[r] = fmaxf(mpos[r], __shfl_xor(mpos[r], o));
            mneg[r] = fminf(mneg[r], __shfl_xor(mneg[r], o));
        }
    }
    if (lcol == 0) {
#pragma unroll
        for (int fi = 0; fi < 4; ++fi)
#pragma unroll
            for (int rg = 0; rg < 4; ++rg) {
                int row = ibase + fi * 16 + rg;
                ppos[(size_t)row * 32 + chunk] = mpos[fi * 4 + rg];
                pneg[(size_t)row * 32 + chunk] = mneg[fi * 4 + rg];
            }
    }
}

// ---------------- finalize rows + global mean (last-block ticket) ------------
__global__ void triplet_reduce(const float* __restrict__ ppos,
                               const float* __restrict__ pneg,
                               const float* __restrict__ norms,
                               float* __restrict__ gacc,
                               float* __restrict__ out) {
    __shared__ float ss[256];
    __shared__ float sc[256];
    const int tid = threadIdx.x;
    const int r   = blockIdx.x * 256 + tid;
    float mp = -1e38f, mn = 1e38f;
    const f32x4* pp = (const f32x4*)(ppos + (size_t)r * 32);
    const f32x4* pn = (const f32x4*)(pneg + (size_t)r * 32);
#pragma unroll
    for (int s4 = 0; s4 < 8; ++s4) {
        f32x4 a = pp[s4], b = pn[s4];
#pragma unroll
        for (int e = 0; e < 4; ++e) { mp = fmaxf(mp, a[e]); mn = fminf(mn, b[e]); }
    }
    float ni = norms[r];
    bool valid = (mp > -1e37f) && (mn < 1e37f);
    float hp = sqrtf(fmaxf(ni + mp, 0.f));
    float hn = sqrtf(fmaxf(ni + mn, 0.f));
    float pr = fmaxf(hp - hn + MARGIN, 0.f);
    ss[tid] = valid ? pr : 0.f;
    sc[tid] = valid ? 1.f : 0.f;
    __syncthreads();
    for (int o = 128; o > 0; o >>= 1) {
        if (tid < o) { ss[tid] += ss[tid + o]; sc[tid] += sc[tid + o]; }
        __syncthreads();
    }
    if (tid == 0) {
        atomicAdd(&gacc[0], ss[0]);
        atomicAdd(&gacc[1], sc[0]);
        __threadfence();
        unsigned* ticket = (unsigned*)(gacc + 2);
        unsigned old = atomicAdd(ticket, 1u);
        if (old == gridDim.x - 1) {
            float s = atomicAdd(&gacc[0], 0.f);
            float c = atomicAdd(&gacc[1], 0.f);
            out[0] = (c > 0.f) ? (s / c) : 0.f;
        }
    }
}

// -----------------------------------------------------------------------------
extern "C" void kernel_launch(void* const* d_in, const int* in_sizes, int n_in,
                              void* d_out, int out_size, void* d_ws, size_t ws_size,
                              hipStream_t stream) {
    const float* x      = (const float*)d_in[0];
    const int*   labels = (const int*)d_in[1];
    float*       out    = (float*)d_out;

    // ws layout: xh (2 MiB) | norms (32 KiB) | ppos (1 MiB) | pneg (1 MiB) | gacc (12 B)
    char*   ws    = (char*)d_ws;
    half_t* xh    = (half_t*)ws;
    float*  norms = (float*)(ws + (size_t)N * D * sizeof(half_t));
    float*  ppos  = norms + N;
    float*  pneg  = ppos + (size_t)N * 32;
    float*  gacc  = pneg + (size_t)N * 32;

    triplet_prep  <<<N / 4,   256, 0, stream>>>(x, xh, norms, gacc);
    triplet_main  <<<1024,    256, 0, stream>>>(xh, norms, labels, ppos, pneg);
    triplet_reduce<<<N / 256, 256, 0, stream>>>(ppos, pneg, norms, gacc, out);
}

// Round 6
// 61.529 us; speedup vs baseline: 2.8194x; 2.8194x over previous
//
#include <hip/hip_runtime.h>
#include <hip/hip_fp16.h>

#define N 8192
#define D 128
#define MARGIN 0.3f

typedef __fp16 half_t;
typedef __attribute__((ext_vector_type(8))) __fp16 half8;
typedef __attribute__((ext_vector_type(4))) float f32x4;

// ---------------- prep: fp32 -> fp16, exact fp32 norms, zero accumulators ----
__global__ void triplet_prep(const float* __restrict__ x,
                             half_t* __restrict__ xh,
                             float* __restrict__ norms,
                             float* __restrict__ gacc) {
    const int gt = blockIdx.x * 256 + threadIdx.x;
    if (gt < 3) gacc[gt] = 0.f;          // [0]=sum [1]=count [2]=ticket
    const int row  = gt >> 6;            // one wave per row
    const int lane = gt & 63;
    const float* rp = x + (size_t)row * D;
    float a0 = rp[lane], a1 = rp[lane + 64];
    xh[(size_t)row * D + lane]      = (half_t)a0;
    xh[(size_t)row * D + lane + 64] = (half_t)a1;
    float s = fmaf(a0, a0, a1 * a1);
#pragma unroll
    for (int o = 32; o > 0; o >>= 1) s += __shfl_xor(s, o);
    if (lane == 0) norms[row] = s;
}

// ---------------- main: barrier-free register GEMM over L2 -------------------
// 4096 independent waves (1024 blocks x 4 = exactly 4 blocks/CU at VGPR<=128).
// wave = rowgroup (64 rows) x chunk (256 cols). A frags register-resident,
// pre-scaled by -2; acc seeded with n_j so acc = n_j - 2g. 3-deep rotating
// register prefetch of B. No LDS, no barriers, no launch_bounds min-waves.

#define PF(BN, LJN, NJN, SN) {                                          \
    const int jn = colbase + (SN) * 16 + lcol;                          \
    const half_t* bp = xh + (size_t)jn * D + lrow * 8;                  \
    BN[0] = *(const half8*)bp;                                          \
    BN[1] = *(const half8*)(bp + 32);                                   \
    BN[2] = *(const half8*)(bp + 64);                                   \
    BN[3] = *(const half8*)(bp + 96);                                   \
    LJN = labels[jn];                                                   \
    NJN = norms[jn];                                                    \
}

#define POISON(ACC) {                                                   \
    _Pragma("unroll")                                                   \
    for (int rg = 0; rg < 4; ++rg)                                      \
        ACC[rg] = (diagl && rg == drg) ? -1e30f : ACC[rg];              \
}

#define EPI(ACC, FI, LJC) {                                             \
    _Pragma("unroll")                                                   \
    for (int rg = 0; rg < 4; ++rg) {                                    \
        float c = ACC[rg];                                              \
        bool same = (li[(FI) * 4 + rg] == (LJC));                       \
        mpos[(FI)*4+rg] = same ? fmaxf(mpos[(FI)*4+rg], c) : mpos[(FI)*4+rg]; \
        mneg[(FI)*4+rg] = same ? mneg[(FI)*4+rg] : fminf(mneg[(FI)*4+rg], c); \
    }                                                                   \
}

#define COMP(BC, LJC, NJC, S) {                                         \
    f32x4 njq = {NJC, NJC, NJC, NJC};                                   \
    __builtin_amdgcn_s_setprio(1);                                      \
    f32x4 a0 = __builtin_amdgcn_mfma_f32_16x16x32_f16(af[0][0], BC[0], njq, 0, 0, 0); \
    f32x4 a1 = __builtin_amdgcn_mfma_f32_16x16x32_f16(af[1][0], BC[0], njq, 0, 0, 0); \
    f32x4 a2 = __builtin_amdgcn_mfma_f32_16x16x32_f16(af[2][0], BC[0], njq, 0, 0, 0); \
    f32x4 a3 = __builtin_amdgcn_mfma_f32_16x16x32_f16(af[3][0], BC[0], njq, 0, 0, 0); \
    _Pragma("unroll")                                                   \
    for (int ks = 1; ks < 4; ++ks) {                                    \
        a0 = __builtin_amdgcn_mfma_f32_16x16x32_f16(af[0][ks], BC[ks], a0, 0, 0, 0); \
        a1 = __builtin_amdgcn_mfma_f32_16x16x32_f16(af[1][ks], BC[ks], a1, 0, 0, 0); \
        a2 = __builtin_amdgcn_mfma_f32_16x16x32_f16(af[2][ks], BC[ks], a2, 0, 0, 0); \
        a3 = __builtin_amdgcn_mfma_f32_16x16x32_f16(af[3][ks], BC[ks], a3, 0, 0, 0); \
    }                                                                   \
    __builtin_amdgcn_s_setprio(0);                                      \
    const int dj = colbase + (S) * 16 - rowbase;                        \
    if (dj == 0)       POISON(a0)                                       \
    else if (dj == 16) POISON(a1)                                       \
    else if (dj == 32) POISON(a2)                                       \
    else if (dj == 48) POISON(a3)                                       \
    EPI(a0, 0, LJC)                                                     \
    EPI(a1, 1, LJC)                                                     \
    EPI(a2, 2, LJC)                                                     \
    EPI(a3, 3, LJC)                                                     \
}

__launch_bounds__(256, 2)
__global__ void triplet_main(const half_t* __restrict__ xh,
                             const float* __restrict__ norms,
                             const int* __restrict__ labels,
                             float* __restrict__ ppos,
                             float* __restrict__ pneg) {
    const int tid   = threadIdx.x;
    const int lane  = tid & 63;
    const int gw    = blockIdx.x * 4 + (tid >> 6);  // 0..4095
    const int rowg  = gw >> 5;                      // 0..127
    const int chunk = gw & 31;                      // 0..31
    const int lrow  = lane >> 4;                    // 0..3 (k-slot group / C row-group)
    const int lcol  = lane & 15;                    // 0..15 (A/B row, C col)
    const int rowbase = rowg * 64;
    const int colbase = chunk * 256;
    const bool diagl = (lrow == (lcol >> 2));
    const int  drg   = lcol & 3;

    // A fragments: row = rowbase + fi*16 + lcol, k = ks*32 + lrow*8; pre-scaled by -2
    half8 af[4][4];
#pragma unroll
    for (int fi = 0; fi < 4; ++fi) {
        const half_t* ap = xh + (size_t)(rowbase + fi * 16 + lcol) * D + lrow * 8;
#pragma unroll
        for (int ks = 0; ks < 4; ++ks)
            af[fi][ks] = *(const half8*)(ap + ks * 32) * (half_t)(-2.0f);
    }

    // owned C-rows: rowbase + fi*16 + lrow*4 + rg
    const int ibase = rowbase + lrow * 4;
    int li[16];
#pragma unroll
    for (int fi = 0; fi < 4; ++fi)
#pragma unroll
        for (int rg = 0; rg < 4; ++rg)
            li[fi * 4 + rg] = labels[ibase + fi * 16 + rg];

    float mpos[16], mneg[16];
#pragma unroll
    for (int r = 0; r < 16; ++r) { mpos[r] = -1e38f; mneg[r] = 1e38f; }

    // 16 sub-steps of 16 cols, 3-deep rotating register prefetch, no barriers
    half8 b0[4], b1[4], b2[4];
    int lj0, lj1, lj2; float nj0, nj1, nj2;
    PF(b0, lj0, nj0, 0)
    PF(b1, lj1, nj1, 1)
    for (int s = 0; s < 12; s += 3) {           // s = 0,3,6,9 -> COMP 0..11
        PF(b2, lj2, nj2, s + 2)
        COMP(b0, lj0, nj0, s)
        PF(b0, lj0, nj0, s + 3)
        COMP(b1, lj1, nj1, s + 1)
        PF(b1, lj1, nj1, s + 4)
        COMP(b2, lj2, nj2, s + 2)
    }
    // tail: b0 holds 12, b1 holds 13
    PF(b2, lj2, nj2, 14)
    COMP(b0, lj0, nj0, 12)
    PF(b0, lj0, nj0, 15)
    COMP(b1, lj1, nj1, 13)
    COMP(b2, lj2, nj2, 14)
    COMP(b0, lj0, nj0, 15)

    // reduce across the 16 col-lanes (C cols live on lcol)
#pragma unroll
    for (int o = 1; o < 16; o <<= 1) {
#pragma unroll
        for (int r = 0; r < 16; ++r) {
            mpos[r] = fmaxf(mpos[r], __shfl_xor(mpos[r], o));
            mneg[r] = fminf(mneg[r], __shfl_xor(mneg[r], o));
        }
    }
    if (lcol == 0) {
#pragma unroll
        for (int fi = 0; fi < 4; ++fi)
#pragma unroll
            for (int rg = 0; rg < 4; ++rg) {
                int row = ibase + fi * 16 + rg;
                ppos[(size_t)row * 32 + chunk] = mpos[fi * 4 + rg];
                pneg[(size_t)row * 32 + chunk] = mneg[fi * 4 + rg];
            }
    }
}

// ---------------- finalize rows + global mean (last-block ticket) ------------
__global__ void triplet_reduce(const float* __restrict__ ppos,
                               const float* __restrict__ pneg,
                               const float* __restrict__ norms,
                               float* __restrict__ gacc,
                               float* __restrict__ out) {
    __shared__ float ss[256];
    __shared__ float sc[256];
    const int tid = threadIdx.x;
    const int r   = blockIdx.x * 256 + tid;
    float mp = -1e38f, mn = 1e38f;
    const f32x4* pp = (const f32x4*)(ppos + (size_t)r * 32);
    const f32x4* pn = (const f32x4*)(pneg + (size_t)r * 32);
#pragma unroll
    for (int s4 = 0; s4 < 8; ++s4) {
        f32x4 a = pp[s4], b = pn[s4];
#pragma unroll
        for (int e = 0; e < 4; ++e) { mp = fmaxf(mp, a[e]); mn = fminf(mn, b[e]); }
    }
    float ni = norms[r];
    bool valid = (mp > -1e37f) && (mn < 1e37f);
    float hp = sqrtf(fmaxf(ni + mp, 0.f));
    float hn = sqrtf(fmaxf(ni + mn, 0.f));
    float pr = fmaxf(hp - hn + MARGIN, 0.f);
    ss[tid] = valid ? pr : 0.f;
    sc[tid] = valid ? 1.f : 0.f;
    __syncthreads();
    for (int o = 128; o > 0; o >>= 1) {
        if (tid < o) { ss[tid] += ss[tid + o]; sc[tid] += sc[tid + o]; }
        __syncthreads();
    }
    if (tid == 0) {
        atomicAdd(&gacc[0], ss[0]);
        atomicAdd(&gacc[1], sc[0]);
        __threadfence();
        unsigned* ticket = (unsigned*)(gacc + 2);
        unsigned old = atomicAdd(ticket, 1u);
        if (old == gridDim.x - 1) {
            float s = atomicAdd(&gacc[0], 0.f);
            float c = atomicAdd(&gacc[1], 0.f);
            out[0] = (c > 0.f) ? (s / c) : 0.f;
        }
    }
}

// -----------------------------------------------------------------------------
extern "C" void kernel_launch(void* const* d_in, const int* in_sizes, int n_in,
                              void* d_out, int out_size, void* d_ws, size_t ws_size,
                              hipStream_t stream) {
    const float* x      = (const float*)d_in[0];
    const int*   labels = (const int*)d_in[1];
    float*       out    = (float*)d_out;

    // ws layout: xh (2 MiB) | norms (32 KiB) | ppos (1 MiB) | pneg (1 MiB) | gacc (12 B)
    char*   ws    = (char*)d_ws;
    half_t* xh    = (half_t*)ws;
    float*  norms = (float*)(ws + (size_t)N * D * sizeof(half_t));
    float*  ppos  = norms + N;
    float*  pneg  = ppos + (size_t)N * 32;
    float*  gacc  = pneg + (size_t)N * 32;

    triplet_prep  <<<N / 4,   256, 0, stream>>>(x, xh, norms, gacc);
    triplet_main  <<<1024,    256, 0, stream>>>(xh, norms, labels, ppos, pneg);
    triplet_reduce<<<N / 256, 256, 0, stream>>>(ppos, pneg, norms, gacc, out);
}

// Round 7
// 48.504 us; speedup vs baseline: 3.5765x; 1.2685x over previous
//
#include <hip/hip_runtime.h>
#include <hip/hip_fp16.h>

#define N 8192
#define D 128
#define MARGIN 0.3f

typedef __fp16 half_t;
typedef __attribute__((ext_vector_type(8))) __fp16 half8;
typedef __attribute__((ext_vector_type(4))) float f32x4;

// ---------------- prep 1: exact fp32 norms + zero accumulators ---------------
__global__ void triplet_norm(const float* __restrict__ x,
                             float* __restrict__ norms,
                             float* __restrict__ gacc) {
    const int gt = blockIdx.x * 256 + threadIdx.x;
    if (gt < 3) gacc[gt] = 0.f;          // [0]=sum [1]=count [2]=ticket
    const int row  = gt >> 6;            // one wave per row
    const int lane = gt & 63;
    const float* rp = x + (size_t)row * D;
    float a0 = rp[lane], a1 = rp[lane + 64];
    float s = fmaf(a0, a0, a1 * a1);
#pragma unroll
    for (int o = 32; o > 0; o >>= 1) s += __shfl_xor(s, o);
    if (lane == 0) norms[row] = s;
}

// ---------------- prep 2: fp32 -> fp16 packed MFMA-native tiles --------------
// xp[tile][ks][lane][e] : tile = j>>4, lane = lrow*16 + (j&15), k = ks*32+lrow*8+e.
// Flat: xp[((t*4 + ks)*64 + lane)*8 + e]  ==  xp[gid*8] for gid = t*256 + i.
__global__ void triplet_pack(const float* __restrict__ x,
                             half_t* __restrict__ xp) {
    const int gid = blockIdx.x * 256 + threadIdx.x;   // 0..131071
    const int t   = gid >> 8;
    const int i   = gid & 255;
    const int row = t * 16 + (i & 15);
    const int k0  = ((i >> 4) & 15) * 8;
    const float* rp = x + (size_t)row * D + k0;
    half_t v[8];
#pragma unroll
    for (int e = 0; e < 8; ++e) v[e] = (half_t)rp[e];
    *(half8*)(xp + (size_t)gid * 8) = *(const half8*)v;
}

// ---------------- main: barrier-free register GEMM over L2 -------------------
// 2048 independent waves (512 blocks x 4). wave = rowgroup (64 rows) x chunk (512 cols).
// A frags register-resident, pre-scaled by -2; acc seeded with n_j so acc = n_j - 2g.
// Packed layout => every fragment load is base + lane*16B (1KB contiguous/instr).
// 3-deep rotating register prefetch. No LDS, no barriers.

#define PF(BN, LJN, NJN, SN) {                                          \
    const half_t* bp = xp + ((size_t)(colbase >> 4) + (SN)) * 2048 + lane * 8; \
    BN[0] = *(const half8*)bp;                                          \
    BN[1] = *(const half8*)(bp + 512);                                  \
    BN[2] = *(const half8*)(bp + 1024);                                 \
    BN[3] = *(const half8*)(bp + 1536);                                 \
    const int jn = colbase + (SN) * 16 + lcol;                          \
    LJN = labels[jn];                                                   \
    NJN = norms[jn];                                                    \
}

#define POISON(ACC) {                                                   \
    _Pragma("unroll")                                                   \
    for (int rg = 0; rg < 4; ++rg)                                      \
        ACC[rg] = (diagl && rg == drg) ? -1e30f : ACC[rg];              \
}

#define EPI(ACC, FI, LJC) {                                             \
    _Pragma("unroll")                                                   \
    for (int rg = 0; rg < 4; ++rg) {                                    \
        float c = ACC[rg];                                              \
        bool same = (li[(FI) * 4 + rg] == (LJC));                       \
        mpos[(FI)*4+rg] = same ? fmaxf(mpos[(FI)*4+rg], c) : mpos[(FI)*4+rg]; \
        mneg[(FI)*4+rg] = same ? mneg[(FI)*4+rg] : fminf(mneg[(FI)*4+rg], c); \
    }                                                                   \
}

#define COMP(BC, LJC, NJC, S) {                                         \
    f32x4 njq = {NJC, NJC, NJC, NJC};                                   \
    __builtin_amdgcn_s_setprio(1);                                      \
    f32x4 a0 = __builtin_amdgcn_mfma_f32_16x16x32_f16(af[0][0], BC[0], njq, 0, 0, 0); \
    f32x4 a1 = __builtin_amdgcn_mfma_f32_16x16x32_f16(af[1][0], BC[0], njq, 0, 0, 0); \
    f32x4 a2 = __builtin_amdgcn_mfma_f32_16x16x32_f16(af[2][0], BC[0], njq, 0, 0, 0); \
    f32x4 a3 = __builtin_amdgcn_mfma_f32_16x16x32_f16(af[3][0], BC[0], njq, 0, 0, 0); \
    _Pragma("unroll")                                                   \
    for (int ks = 1; ks < 4; ++ks) {                                    \
        a0 = __builtin_amdgcn_mfma_f32_16x16x32_f16(af[0][ks], BC[ks], a0, 0, 0, 0); \
        a1 = __builtin_amdgcn_mfma_f32_16x16x32_f16(af[1][ks], BC[ks], a1, 0, 0, 0); \
        a2 = __builtin_amdgcn_mfma_f32_16x16x32_f16(af[2][ks], BC[ks], a2, 0, 0, 0); \
        a3 = __builtin_amdgcn_mfma_f32_16x16x32_f16(af[3][ks], BC[ks], a3, 0, 0, 0); \
    }                                                                   \
    __builtin_amdgcn_s_setprio(0);                                      \
    const int dj = colbase + (S) * 16 - rowbase;                        \
    if (dj == 0)       POISON(a0)                                       \
    else if (dj == 16) POISON(a1)                                       \
    else if (dj == 32) POISON(a2)                                       \
    else if (dj == 48) POISON(a3)                                       \
    EPI(a0, 0, LJC)                                                     \
    EPI(a1, 1, LJC)                                                     \
    EPI(a2, 2, LJC)                                                     \
    EPI(a3, 3, LJC)                                                     \
}

__launch_bounds__(256, 2)
__global__ void triplet_main(const half_t* __restrict__ xp,
                             const float* __restrict__ norms,
                             const int* __restrict__ labels,
                             float* __restrict__ ppos,
                             float* __restrict__ pneg) {
    const int tid   = threadIdx.x;
    const int lane  = tid & 63;
    const int gw    = blockIdx.x * 4 + (tid >> 6);  // 0..2047
    const int rowg  = gw >> 4;                      // 0..127
    const int chunk = gw & 15;                      // 0..15
    const int lrow  = lane >> 4;                    // 0..3 (k-slot group / C row-group)
    const int lcol  = lane & 15;                    // 0..15 (A/B row, C col)
    const int rowbase = rowg * 64;
    const int colbase = chunk * 512;
    const bool diagl = (lrow == (lcol >> 2));
    const int  drg   = lcol & 3;

    // A fragments from packed tiles (rowg*4 + fi); pre-scaled by -2
    half8 af[4][4];
#pragma unroll
    for (int fi = 0; fi < 4; ++fi) {
        const half_t* ap = xp + ((size_t)(rowbase >> 4) + fi) * 2048 + lane * 8;
#pragma unroll
        for (int ks = 0; ks < 4; ++ks)
            af[fi][ks] = *(const half8*)(ap + ks * 512) * (half_t)(-2.0f);
    }

    // owned C-rows: rowbase + fi*16 + lrow*4 + rg
    const int ibase = rowbase + lrow * 4;
    int li[16];
#pragma unroll
    for (int fi = 0; fi < 4; ++fi)
#pragma unroll
        for (int rg = 0; rg < 4; ++rg)
            li[fi * 4 + rg] = labels[ibase + fi * 16 + rg];

    float mpos[16], mneg[16];
#pragma unroll
    for (int r = 0; r < 16; ++r) { mpos[r] = -1e38f; mneg[r] = 1e38f; }

    // 32 sub-steps of 16 cols, 3-deep rotating register prefetch, no barriers
    half8 b0[4], b1[4], b2[4];
    int lj0, lj1, lj2; float nj0, nj1, nj2;
    PF(b0, lj0, nj0, 0)
    PF(b1, lj1, nj1, 1)
    for (int s = 0; s < 30; s += 3) {
        PF(b2, lj2, nj2, s + 2)
        COMP(b0, lj0, nj0, s)
        PF(b0, lj0, nj0, s + 3)
        COMP(b1, lj1, nj1, s + 1)
        PF(b1, lj1, nj1, s + 4)
        COMP(b2, lj2, nj2, s + 2)
    }
    COMP(b0, lj0, nj0, 30)
    COMP(b1, lj1, nj1, 31)

    // reduce across the 16 col-lanes (C cols live on lcol)
#pragma unroll
    for (int o = 1; o < 16; o <<= 1) {
#pragma unroll
        for (int r = 0; r < 16; ++r) {
            mpos[r] = fmaxf(mpos[r], __shfl_xor(mpos[r], o));
            mneg[r] = fminf(mneg[r], __shfl_xor(mneg[r], o));
        }
    }
    if (lcol == 0) {
#pragma unroll
        for (int fi = 0; fi < 4; ++fi)
#pragma unroll
            for (int rg = 0; rg < 4; ++rg) {
                int row = ibase + fi * 16 + rg;
                ppos[(size_t)row * 16 + chunk] = mpos[fi * 4 + rg];
                pneg[(size_t)row * 16 + chunk] = mneg[fi * 4 + rg];
            }
    }
}

// ---------------- finalize rows + global mean (last-block ticket) ------------
__global__ void triplet_reduce(const float* __restrict__ ppos,
                               const float* __restrict__ pneg,
                               const float* __restrict__ norms,
                               float* __restrict__ gacc,
                               float* __restrict__ out) {
    __shared__ float ss[256];
    __shared__ float sc[256];
    const int tid = threadIdx.x;
    const int r   = blockIdx.x * 256 + tid;
    float mp = -1e38f, mn = 1e38f;
    const f32x4* pp = (const f32x4*)(ppos + (size_t)r * 16);
    const f32x4* pn = (const f32x4*)(pneg + (size_t)r * 16);
#pragma unroll
    for (int s4 = 0; s4 < 4; ++s4) {
        f32x4 a = pp[s4], b = pn[s4];
#pragma unroll
        for (int e = 0; e < 4; ++e) { mp = fmaxf(mp, a[e]); mn = fminf(mn, b[e]); }
    }
    float ni = norms[r];
    bool valid = (mp > -1e37f) && (mn < 1e37f);
    float hp = sqrtf(fmaxf(ni + mp, 0.f));
    float hn = sqrtf(fmaxf(ni + mn, 0.f));
    float pr = fmaxf(hp - hn + MARGIN, 0.f);
    ss[tid] = valid ? pr : 0.f;
    sc[tid] = valid ? 1.f : 0.f;
    __syncthreads();
    for (int o = 128; o > 0; o >>= 1) {
        if (tid < o) { ss[tid] += ss[tid + o]; sc[tid] += sc[tid + o]; }
        __syncthreads();
    }
    if (tid == 0) {
        atomicAdd(&gacc[0], ss[0]);
        atomicAdd(&gacc[1], sc[0]);
        __threadfence();
        unsigned* ticket = (unsigned*)(gacc + 2);
        unsigned old = atomicAdd(ticket, 1u);
        if (old == gridDim.x - 1) {
            float s = atomicAdd(&gacc[0], 0.f);
            float c = atomicAdd(&gacc[1], 0.f);
            out[0] = (c > 0.f) ? (s / c) : 0.f;
        }
    }
}

// -----------------------------------------------------------------------------
extern "C" void kernel_launch(void* const* d_in, const int* in_sizes, int n_in,
                              void* d_out, int out_size, void* d_ws, size_t ws_size,
                              hipStream_t stream) {
    const float* x      = (const float*)d_in[0];
    const int*   labels = (const int*)d_in[1];
    float*       out    = (float*)d_out;

    // ws layout: xp (2 MiB) | norms (32 KiB) | ppos (512 KiB) | pneg (512 KiB) | gacc (12 B)
    char*   ws    = (char*)d_ws;
    half_t* xp    = (half_t*)ws;
    float*  norms = (float*)(ws + (size_t)N * D * sizeof(half_t));
    float*  ppos  = norms + N;
    float*  pneg  = ppos + (size_t)N * 16;
    float*  gacc  = pneg + (size_t)N * 16;

    triplet_norm  <<<N / 4,        256, 0, stream>>>(x, norms, gacc);
    triplet_pack  <<<N * 16 / 256, 256, 0, stream>>>(x, xp);
    triplet_main  <<<512,          256, 0, stream>>>(xp, norms, labels, ppos, pneg);
    triplet_reduce<<<N / 256,      256, 0, stream>>>(ppos, pneg, norms, gacc, out);
}